// Round 1
// baseline (782.575 us; speedup 1.0000x reference)
//
#include <hip/hip_runtime.h>
#include <stdint.h>

#define LSEQ 1024
#define NB 4
#define KNB 48
#define NPAIR 25
#define NFEAT 416   // 16 + 25*16
#define NOUT 128
#define NNODE (NB*LSEQ)

// static device scratch (~2.2 MB) -- fully rewritten every call before use
__device__ float4 g_atoms[NNODE*5];
__device__ float4 g_ca[NNODE];
__device__ float  g_wt[NFEAT*NOUT];
__device__ int    g_nbr[NNODE*KNB];
__device__ float  g_dnb[NNODE*KNB];

__constant__ int cPA[24] = {0,2,3,4,1,1,1,1,0,0,0,4,4,3,0,2,3,4,2,3,4,2,3,2};
__constant__ int cPB[24] = {0,2,3,4,0,2,3,4,2,3,4,2,3,2,1,1,1,1,0,0,0,4,4,3};
__constant__ float cMU[16] = {
  2.0f, 3.3333333333f, 4.6666666667f, 6.0f,
  7.3333333333f, 8.6666666667f, 10.0f, 11.3333333333f,
  12.6666666667f, 14.0f, 15.3333333333f, 16.6666666667f,
  18.0f, 19.3333333333f, 20.6666666667f, 22.0f};

__device__ __forceinline__ unsigned long long shfl_xor_u64(unsigned long long x, int m) {
  unsigned hi = __shfl_xor((unsigned)(x >> 32), m, 64);
  unsigned lo = __shfl_xor((unsigned)(x & 0xffffffffu), m, 64);
  return ((unsigned long long)hi << 32) | lo;
}

// ---------------- kernel 0: Cb + atom packing ----------------
__global__ void k_prep(const float* __restrict__ X) {
  int t = blockIdx.x*256 + threadIdx.x;
  if (t >= NNODE) return;
  const float* p = X + (size_t)t*12;
  float nx=p[0],ny=p[1],nz=p[2];
  float cax=p[3],cay=p[4],caz=p[5];
  float cx=p[6],cy=p[7],cz=p[8];
  float ox=p[9],oy=p[10],oz=p[11];
  float bx=cax-nx, by=cay-ny, bz=caz-nz;
  float ex=cx-cax, ey=cy-cay, ez=cz-caz;
  float ax2 = by*ez - bz*ey;
  float ay2 = bz*ex - bx*ez;
  float az2 = bx*ey - by*ex;
  float cbx = -0.58273431f*ax2 + 0.56802827f*bx - 0.54067466f*ex + cax;
  float cby = -0.58273431f*ay2 + 0.56802827f*by - 0.54067466f*ey + cay;
  float cbz = -0.58273431f*az2 + 0.56802827f*bz - 0.54067466f*ez + caz;
  g_atoms[t*5+0] = make_float4(nx,ny,nz,0.f);
  g_atoms[t*5+1] = make_float4(cax,cay,caz,0.f);
  g_atoms[t*5+2] = make_float4(cx,cy,cz,0.f);
  g_atoms[t*5+3] = make_float4(ox,oy,oz,0.f);
  g_atoms[t*5+4] = make_float4(cbx,cby,cbz,0.f);
  g_ca[t] = make_float4(cax,cay,caz,0.f);
}

// ---------------- kernel 0b: transpose W_edge -> [f/4][e][4] ----------------
__global__ void k_wt(const float* __restrict__ W) {
  int t = blockIdx.x*256 + threadIdx.x;
  if (t >= NOUT*NFEAT) return;
  int f4  = t >> 9;       // /512
  int rem = t & 511;
  int e   = rem >> 2;
  int d   = rem & 3;
  g_wt[t] = W[e*NFEAT + f4*4 + d];
}

// ---------------- kernel 1: exact top-K (bit-exact D, stable ties) ----------------
__global__ __launch_bounds__(256) void k_topk(const float* __restrict__ mask,
                                              float* __restrict__ outIdx) {
  __shared__ float4 sca[LSEQ];
  __shared__ float  sm[LSEQ];
  int b = blockIdx.y;
  for (int t = threadIdx.x; t < LSEQ; t += 256) {
    sca[t] = g_ca[b*LSEQ + t];
    sm[t]  = mask[b*LSEQ + t];
  }
  __syncthreads();
  int wave = threadIdx.x >> 6, lane = threadIdx.x & 63;
  int i = blockIdx.x*4 + wave;
  float4 ci = sca[i];
  float  mi = sm[i];

  float Dv[16];
  float dmax = 0.f;
  #pragma unroll
  for (int q = 0; q < 16; ++q) {
    int j = lane + (q << 6);
    float4 cj = sca[j];
    // bit-exact vs XLA: separate mul/add (no FMA), correctly-rounded sqrt
    float dx = __fsub_rn(cj.x, ci.x);
    float dy = __fsub_rn(cj.y, ci.y);
    float dz = __fsub_rn(cj.z, ci.z);
    float s  = __fadd_rn(__fadd_rn(__fmul_rn(dx,dx), __fmul_rn(dy,dy)), __fmul_rn(dz,dz));
    float sq = __fsqrt_rn(__fadd_rn(s, 1e-6f));
    float d  = __fmul_rn(__fmul_rn(mi, sm[j]), sq);   // mask2 * sqrt(...)
    Dv[q] = d;
    dmax = fmaxf(dmax, d);
  }
  #pragma unroll
  for (int o = 32; o; o >>= 1) dmax = fmaxf(dmax, __shfl_xor(dmax, o, 64));

  unsigned long long key[16];
  unsigned long long lmin = ~0ull;
  #pragma unroll
  for (int q = 0; q < 16; ++q) {
    int j = lane + (q << 6);
    float m2   = __fmul_rn(mi, sm[j]);
    float dadj = __fadd_rn(Dv[q], __fmul_rn(__fsub_rn(1.0f, m2), dmax));
    key[q] = ((unsigned long long)__float_as_uint(dadj) << 32) | (unsigned)j;
    lmin = (key[q] < lmin) ? key[q] : lmin;
  }

  size_t row = (size_t)(b*LSEQ + i);
  for (int k = 0; k < KNB; ++k) {
    unsigned long long m = lmin;
    #pragma unroll
    for (int o = 1; o < 64; o <<= 1) {
      unsigned long long other = shfl_xor_u64(m, o);
      m = (other < m) ? other : m;
    }
    if (lane == 0) {
      unsigned j = (unsigned)(m & 0xffffffffu);
      g_nbr[row*KNB + k] = (int)j;
      g_dnb[row*KNB + k] = __uint_as_float((unsigned)(m >> 32));
      outIdx[row*KNB + k] = (float)(int)j;
    }
    if (m == lmin) {                 // unique owner (index in low bits)
      unsigned long long nm = ~0ull;
      #pragma unroll
      for (int q = 0; q < 16; ++q) {
        if (key[q] == m) key[q] = ~0ull;
        nm = (key[q] < nm) ? key[q] : nm;
      }
      lmin = nm;
    }
  }
}

// ---------------- kernel 2: features + matvec + layernorm ----------------
__global__ __launch_bounds__(256) void k_edge(
    const int* __restrict__ ridx, const int* __restrict__ chain,
    const float* __restrict__ Wpos, const float* __restrict__ bpos,
    const float* __restrict__ lng, const float* __restrict__ lnb,
    float* __restrict__ out)
{
  __shared__ float  feat[KNB*NFEAT];   // 79,872 B (reused as E_raw later)
  __shared__ float4 atN[KNB*5];
  __shared__ float4 atI[5];
  __shared__ float  dist[KNB*NPAIR];
  __shared__ int    snbr[KNB];
  __shared__ float  sdn[KNB];
  __shared__ int    sdd[KNB];

  int node = blockIdx.x;               // b*LSEQ + i
  int b = node >> 10;
  size_t ebase = (size_t)node * KNB;
  int t = threadIdx.x;

  if (t < KNB) { snbr[t] = g_nbr[ebase + t]; sdn[t] = g_dnb[ebase + t]; }
  if (t >= 64 && t < 69) atI[t-64] = g_atoms[node*5 + (t-64)];
  __syncthreads();

  // positional bucket per edge + neighbor atom gather
  if (t < KNB) {
    int j = snbr[t];
    int off = ridx[node] - ridx[b*LSEQ + j];
    bool same = (chain[node] == chain[b*LSEQ + j]);
    int dcl = min(max(off + 32, 0), 64);
    sdd[t] = same ? dcl : 65;
  }
  for (int u = t; u < KNB*5; u += 256) {
    int k = u / 5, a = u % 5;
    atN[u] = g_atoms[(b*LSEQ + snbr[k])*5 + a];
  }
  __syncthreads();

  // E_pos (features 0..15)
  for (int u = t; u < KNB*16; u += 256) {
    int k = u >> 4, c = u & 15;
    feat[k*NFEAT + c] = Wpos[c*66 + sdd[k]] + bpos[c];
  }
  // 25 distances per edge
  for (int u = t; u < KNB*NPAIR; u += 256) {
    int k = u / NPAIR, p = u % NPAIR;
    float d;
    if (p == 0) d = sdn[k];
    else {
      float4 A = atI[cPA[p-1]];
      float4 Bv = atN[k*5 + cPB[p-1]];
      float dx = A.x - Bv.x, dy = A.y - Bv.y, dz = A.z - Bv.z;
      d = sqrtf(dx*dx + dy*dy + dz*dz + 1e-6f);
    }
    dist[u] = d;
  }
  __syncthreads();

  // RBF expansion (features 16..415)
  for (int u = t; u < KNB*NPAIR; u += 256) {
    int k = u / NPAIR, p = u % NPAIR;
    float d = dist[u];
    float* fp = &feat[k*NFEAT + 16 + p*16];
    #pragma unroll
    for (int m = 0; m < 16; ++m) {
      float z = (d - cMU[m]) * 0.8f;
      fp[m] = __expf(-z*z);
    }
  }
  __syncthreads();

  // matvec: out[k][e] = sum_f feat[k][f] * W[e][f]
  int e  = t & 127;
  int kb = t >> 7;                      // 0 or 1
  float acc[24];
  #pragma unroll
  for (int z = 0; z < 24; ++z) acc[z] = 0.f;
  for (int f0 = 0; f0 < NFEAT; f0 += 4) {
    const float4 w = *(const float4*)&g_wt[(f0 << 7) + (e << 2)];
    #pragma unroll
    for (int kk = 0; kk < 24; ++kk) {
      const float4 ff = *(const float4*)&feat[(kb + (kk << 1))*NFEAT + f0];
      acc[kk] = fmaf(ff.w, w.w, fmaf(ff.z, w.z, fmaf(ff.y, w.y, fmaf(ff.x, w.x, acc[kk]))));
    }
  }
  __syncthreads();
  float* era = feat;                    // reuse LDS as E_raw[48][128]
  #pragma unroll
  for (int kk = 0; kk < 24; ++kk) era[(kb + (kk << 1))*NOUT + e] = acc[kk];
  __syncthreads();

  // LayerNorm over 128 channels, one wave per row
  int wave = t >> 6, lane = t & 63;
  float g0 = lng[lane], g1 = lng[64+lane];
  float h0 = lnb[lane], h1 = lnb[64+lane];
  for (int r = wave; r < KNB; r += 4) {
    float x0 = era[r*NOUT + lane], x1 = era[r*NOUT + 64 + lane];
    float s  = x0 + x1;
    float sq = x0*x0 + x1*x1;
    #pragma unroll
    for (int o = 32; o; o >>= 1) { s += __shfl_xor(s, o, 64); sq += __shfl_xor(sq, o, 64); }
    float mu  = s * (1.0f/128.0f);
    float var = sq * (1.0f/128.0f) - mu*mu;
    float rs  = rsqrtf(var + 1e-5f);
    size_t ob = (ebase + r) * NOUT;
    out[ob + lane]      = (x0 - mu) * rs * g0 + h0;
    out[ob + 64 + lane] = (x1 - mu) * rs * g1 + h1;
  }
}

extern "C" void kernel_launch(void* const* d_in, const int* in_sizes, int n_in,
                              void* d_out, int out_size, void* d_ws, size_t ws_size,
                              hipStream_t stream) {
  const float* X     = (const float*)d_in[0];
  const float* mask  = (const float*)d_in[1];
  const int*   ridx  = (const int*)d_in[2];
  const int*   chain = (const int*)d_in[3];
  const float* Wpos  = (const float*)d_in[4];
  const float* bpos  = (const float*)d_in[5];
  const float* Wedge = (const float*)d_in[6];
  const float* lng   = (const float*)d_in[7];
  const float* lnb   = (const float*)d_in[8];
  float* out = (float*)d_out;
  float* outIdx = out + (size_t)NNODE*KNB*NOUT;

  k_prep<<<dim3(NNODE/256), dim3(256), 0, stream>>>(X);
  k_wt<<<dim3((NOUT*NFEAT+255)/256), dim3(256), 0, stream>>>(Wedge);
  k_topk<<<dim3(LSEQ/4, NB), dim3(256), 0, stream>>>(mask, outIdx);
  k_edge<<<dim3(NNODE), dim3(256), 0, stream>>>(ridx, chain, Wpos, bpos, lng, lnb, out);
}

// Round 2
// 145.179 us; speedup vs baseline: 5.3904x; 5.3904x over previous
//
#include <hip/hip_runtime.h>
#include <stdint.h>

#define LSEQ 1024
#define NB 4
#define KNB 48
#define NPAIR 25
#define NFEAT 416   // 16 + 25*16
#define NOUT 128
#define NNODE (NB*LSEQ)
#define FPITCH 424  // feat LDS row pitch in bf16 elems (16B-aligned, conflict-reducing)
#define EPITCH 132  // E_raw LDS row pitch in f32

typedef float f32x4 __attribute__((ext_vector_type(4)));
typedef short s16x8 __attribute__((ext_vector_type(8)));

// static device scratch -- fully rewritten every call before use
__device__ float4 g_atoms[NNODE*5];
__device__ float4 g_ca[NNODE];
__device__ ushort g_wbf[NOUT*NFEAT];   // W_edge in bf16, row-major [e][f]
__device__ int    g_nbr[NNODE*KNB];
__device__ float  g_dnb[NNODE*KNB];

__constant__ int cPA[24] = {0,2,3,4,1,1,1,1,0,0,0,4,4,3,0,2,3,4,2,3,4,2,3,2};
__constant__ int cPB[24] = {0,2,3,4,0,2,3,4,2,3,4,2,3,2,1,1,1,1,0,0,0,4,4,3};
__constant__ float cMU[16] = {
  2.0f, 3.3333333333f, 4.6666666667f, 6.0f,
  7.3333333333f, 8.6666666667f, 10.0f, 11.3333333333f,
  12.6666666667f, 14.0f, 15.3333333333f, 16.6666666667f,
  18.0f, 19.3333333333f, 20.6666666667f, 22.0f};

__device__ __forceinline__ ushort f2bf(float x) {
  unsigned u = __float_as_uint(x);
  u += 0x7fffu + ((u >> 16) & 1u);   // round-to-nearest-even
  return (ushort)(u >> 16);
}

__device__ __forceinline__ unsigned long long shfl_xor_u64(unsigned long long x, int m) {
  unsigned hi = __shfl_xor((unsigned)(x >> 32), m, 64);
  unsigned lo = __shfl_xor((unsigned)(x & 0xffffffffu), m, 64);
  return ((unsigned long long)hi << 32) | lo;
}

// ---------------- kernel 0: Cb + atom packing ----------------
__global__ void k_prep(const float* __restrict__ X) {
  int t = blockIdx.x*256 + threadIdx.x;
  if (t >= NNODE) return;
  const float* p = X + (size_t)t*12;
  float nx=p[0],ny=p[1],nz=p[2];
  float cax=p[3],cay=p[4],caz=p[5];
  float cx=p[6],cy=p[7],cz=p[8];
  float ox=p[9],oy=p[10],oz=p[11];
  float bx=cax-nx, by=cay-ny, bz=caz-nz;
  float ex=cx-cax, ey=cy-cay, ez=cz-caz;
  float ax2 = by*ez - bz*ey;
  float ay2 = bz*ex - bx*ez;
  float az2 = bx*ey - by*ex;
  float cbx = -0.58273431f*ax2 + 0.56802827f*bx - 0.54067466f*ex + cax;
  float cby = -0.58273431f*ay2 + 0.56802827f*by - 0.54067466f*ey + cay;
  float cbz = -0.58273431f*az2 + 0.56802827f*bz - 0.54067466f*ez + caz;
  g_atoms[t*5+0] = make_float4(nx,ny,nz,0.f);
  g_atoms[t*5+1] = make_float4(cax,cay,caz,0.f);
  g_atoms[t*5+2] = make_float4(cx,cy,cz,0.f);
  g_atoms[t*5+3] = make_float4(ox,oy,oz,0.f);
  g_atoms[t*5+4] = make_float4(cbx,cby,cbz,0.f);
  g_ca[t] = make_float4(cax,cay,caz,0.f);
}

// ---------------- kernel 0b: W_edge fp32 -> bf16 (same [e][f] layout) ----------------
__global__ void k_wt(const float* __restrict__ W) {
  int t = blockIdx.x*256 + threadIdx.x;
  if (t < NOUT*NFEAT) g_wbf[t] = f2bf(W[t]);
}

// ---------------- kernel 1: exact top-K (bit-exact D, stable ties) ----------------
__global__ __launch_bounds__(256) void k_topk(const float* __restrict__ mask,
                                              float* __restrict__ outIdx) {
  __shared__ float4 sca[LSEQ];
  __shared__ float  sm[LSEQ];
  int b = blockIdx.y;
  for (int t = threadIdx.x; t < LSEQ; t += 256) {
    sca[t] = g_ca[b*LSEQ + t];
    sm[t]  = mask[b*LSEQ + t];
  }
  __syncthreads();
  int wave = threadIdx.x >> 6, lane = threadIdx.x & 63;
  int i = blockIdx.x*4 + wave;
  float4 ci = sca[i];
  float  mi = sm[i];

  float Dv[16];
  float dmax = 0.f;
  #pragma unroll
  for (int q = 0; q < 16; ++q) {
    int j = lane + (q << 6);
    float4 cj = sca[j];
    float dx = __fsub_rn(cj.x, ci.x);
    float dy = __fsub_rn(cj.y, ci.y);
    float dz = __fsub_rn(cj.z, ci.z);
    float s  = __fadd_rn(__fadd_rn(__fmul_rn(dx,dx), __fmul_rn(dy,dy)), __fmul_rn(dz,dz));
    float sq = __fsqrt_rn(__fadd_rn(s, 1e-6f));
    float d  = __fmul_rn(__fmul_rn(mi, sm[j]), sq);
    Dv[q] = d;
    dmax = fmaxf(dmax, d);
  }
  #pragma unroll
  for (int o = 32; o; o >>= 1) dmax = fmaxf(dmax, __shfl_xor(dmax, o, 64));

  unsigned long long key[16];
  unsigned long long lmin = ~0ull;
  #pragma unroll
  for (int q = 0; q < 16; ++q) {
    int j = lane + (q << 6);
    float m2   = __fmul_rn(mi, sm[j]);
    float dadj = __fadd_rn(Dv[q], __fmul_rn(__fsub_rn(1.0f, m2), dmax));
    key[q] = ((unsigned long long)__float_as_uint(dadj) << 32) | (unsigned)j;
    lmin = (key[q] < lmin) ? key[q] : lmin;
  }

  size_t row = (size_t)(b*LSEQ + i);
  for (int k = 0; k < KNB; ++k) {
    unsigned long long m = lmin;
    #pragma unroll
    for (int o = 1; o < 64; o <<= 1) {
      unsigned long long other = shfl_xor_u64(m, o);
      m = (other < m) ? other : m;
    }
    if (lane == 0) {
      unsigned j = (unsigned)(m & 0xffffffffu);
      g_nbr[row*KNB + k] = (int)j;
      g_dnb[row*KNB + k] = __uint_as_float((unsigned)(m >> 32));
      outIdx[row*KNB + k] = (float)(int)j;
    }
    if (m == lmin) {
      unsigned long long nm = ~0ull;
      #pragma unroll
      for (int q = 0; q < 16; ++q) {
        if (key[q] == m) key[q] = ~0ull;
        nm = (key[q] < nm) ? key[q] : nm;
      }
      lmin = nm;
    }
  }
}

// ---------------- kernel 2: features (bf16) + MFMA matmul + layernorm ----------------
__global__ __launch_bounds__(256) void k_edge(
    const int* __restrict__ ridx, const int* __restrict__ chain,
    const float* __restrict__ Wpos, const float* __restrict__ bpos,
    const float* __restrict__ lng, const float* __restrict__ lnb,
    float* __restrict__ out)
{
  // feat (bf16) and E_raw (f32) overlay the same buffer (phases are disjoint)
  __shared__ __align__(16) unsigned char smem[KNB*FPITCH*2];   // 40,704 B
  ushort* featb = (ushort*)smem;
  float*  era   = (float*)smem;                                 // 48*132*4 = 25,344 B
  __shared__ float4 atN[KNB*5];
  __shared__ float4 atI[5];
  __shared__ int    snbr[KNB];
  __shared__ float  sdn[KNB];
  __shared__ int    sdd[KNB];

  int node = blockIdx.x;               // b*LSEQ + i
  int b = node >> 10;
  size_t ebase = (size_t)node * KNB;
  int t = threadIdx.x;

  if (t < KNB) { snbr[t] = g_nbr[ebase + t]; sdn[t] = g_dnb[ebase + t]; }
  if (t >= 64 && t < 69) atI[t-64] = g_atoms[node*5 + (t-64)];
  __syncthreads();

  if (t < KNB) {
    int j = snbr[t];
    int off = ridx[node] - ridx[b*LSEQ + j];
    bool same = (chain[node] == chain[b*LSEQ + j]);
    int dcl = min(max(off + 32, 0), 64);
    sdd[t] = same ? dcl : 65;
  }
  for (int u = t; u < KNB*5; u += 256) {
    int k = u / 5, a = u % 5;
    atN[u] = g_atoms[(b*LSEQ + snbr[k])*5 + a];
  }
  __syncthreads();

  // E_pos (features 0..15), bf16
  if (t < KNB) {
    int dd = sdd[t];
    s16x8 v0, v1;
    #pragma unroll
    for (int c = 0; c < 8; ++c)  v0[c]   = (short)f2bf(Wpos[c*66 + dd] + bpos[c]);
    #pragma unroll
    for (int c = 8; c < 16; ++c) v1[c-8] = (short)f2bf(Wpos[c*66 + dd] + bpos[c]);
    ushort* fp = &featb[t*FPITCH];
    *(s16x8*)fp = v0;
    *(s16x8*)(fp+8) = v1;
  }
  // distance + RBF expansion fused (features 16..415), bf16
  for (int u = t; u < KNB*NPAIR; u += 256) {
    int k = u / NPAIR, p = u % NPAIR;
    float d;
    if (p == 0) d = sdn[k];
    else {
      float4 A = atI[cPA[p-1]];
      float4 Bv = atN[k*5 + cPB[p-1]];
      float dx = A.x-Bv.x, dy = A.y-Bv.y, dz = A.z-Bv.z;
      d = sqrtf(dx*dx + dy*dy + dz*dz + 1e-6f);
    }
    s16x8 v0, v1;
    #pragma unroll
    for (int m = 0; m < 8; ++m)  { float z = (d - cMU[m])*0.8f;   v0[m]   = (short)f2bf(__expf(-z*z)); }
    #pragma unroll
    for (int m = 8; m < 16; ++m) { float z = (d - cMU[m])*0.8f;   v1[m-8] = (short)f2bf(__expf(-z*z)); }
    ushort* fp = &featb[k*FPITCH + 16 + p*16];
    *(s16x8*)fp = v0;
    *(s16x8*)(fp+8) = v1;
  }
  __syncthreads();

  // MFMA GEMM: era[48][128] = feat[48][416] @ W^T[416][128]
  // wave w owns output cols [w*32, w*32+32); 3 M-tiles x 2 N-tiles x 13 K-steps
  int ln = t & 63;
  int wv = t >> 6;
  int fr = ln & 15;          // A row / B col within tile
  int fq = ln >> 4;          // k-chunk (of 8)
  int n0 = wv * 32;
  f32x4 acc[3][2];
  #pragma unroll
  for (int mt = 0; mt < 3; ++mt) { acc[mt][0] = (f32x4)0.f; acc[mt][1] = (f32x4)0.f; }
  const ushort* wb0 = &g_wbf[(n0 + fr)*NFEAT];
  const ushort* wb1 = &g_wbf[(n0 + 16 + fr)*NFEAT];
  for (int k0 = 0; k0 < NFEAT; k0 += 32) {
    int kk = k0 + fq*8;
    s16x8 bf0 = *(const s16x8*)&wb0[kk];
    s16x8 bf1 = *(const s16x8*)&wb1[kk];
    #pragma unroll
    for (int mt = 0; mt < 3; ++mt) {
      s16x8 af = *(const s16x8*)&featb[(mt*16 + fr)*FPITCH + kk];
      acc[mt][0] = __builtin_amdgcn_mfma_f32_16x16x32_bf16(af, bf0, acc[mt][0], 0, 0, 0);
      acc[mt][1] = __builtin_amdgcn_mfma_f32_16x16x32_bf16(af, bf1, acc[mt][1], 0, 0, 0);
    }
  }
  __syncthreads();           // all waves done reading featb before overlay write

  // C/D layout: reg i of lane -> row (fq*4+i), col fr (within 16x16 tile)
  #pragma unroll
  for (int mt = 0; mt < 3; ++mt)
    #pragma unroll
    for (int nt = 0; nt < 2; ++nt)
      #pragma unroll
      for (int i = 0; i < 4; ++i)
        era[(mt*16 + fq*4 + i)*EPITCH + n0 + nt*16 + fr] = acc[mt][nt][i];
  __syncthreads();

  // LayerNorm over 128 channels, one wave per row
  float g0 = lng[ln], g1 = lng[64+ln];
  float h0 = lnb[ln], h1 = lnb[64+ln];
  for (int r = wv; r < KNB; r += 4) {
    float x0 = era[r*EPITCH + ln], x1 = era[r*EPITCH + 64 + ln];
    float s  = x0 + x1;
    float sq = x0*x0 + x1*x1;
    #pragma unroll
    for (int o = 32; o; o >>= 1) { s += __shfl_xor(s, o, 64); sq += __shfl_xor(sq, o, 64); }
    float mu  = s * (1.0f/128.0f);
    float var = sq * (1.0f/128.0f) - mu*mu;
    float rs  = rsqrtf(var + 1e-5f);
    size_t ob = (ebase + r) * NOUT;
    out[ob + ln]      = (x0 - mu) * rs * g0 + h0;
    out[ob + 64 + ln] = (x1 - mu) * rs * g1 + h1;
  }
}

extern "C" void kernel_launch(void* const* d_in, const int* in_sizes, int n_in,
                              void* d_out, int out_size, void* d_ws, size_t ws_size,
                              hipStream_t stream) {
  const float* X     = (const float*)d_in[0];
  const float* mask  = (const float*)d_in[1];
  const int*   ridx  = (const int*)d_in[2];
  const int*   chain = (const int*)d_in[3];
  const float* Wpos  = (const float*)d_in[4];
  const float* bpos  = (const float*)d_in[5];
  const float* Wedge = (const float*)d_in[6];
  const float* lng   = (const float*)d_in[7];
  const float* lnb   = (const float*)d_in[8];
  float* out = (float*)d_out;
  float* outIdx = out + (size_t)NNODE*KNB*NOUT;

  k_prep<<<dim3(NNODE/256), dim3(256), 0, stream>>>(X);
  k_wt<<<dim3((NOUT*NFEAT+255)/256), dim3(256), 0, stream>>>(Wedge);
  k_topk<<<dim3(LSEQ/4, NB), dim3(256), 0, stream>>>(mask, outIdx);
  k_edge<<<dim3(NNODE), dim3(256), 0, stream>>>(ridx, chain, Wpos, bpos, lng, lnb, out);
}

// Round 4
// 110.763 us; speedup vs baseline: 7.0653x; 1.3107x over previous
//
#include <hip/hip_runtime.h>
#include <stdint.h>

#define LSEQ 1024
#define NB 4
#define KNB 48
#define NFEAT 416   // 16 + 25*16
#define NOUT 128
#define NNODE (NB*LSEQ)

typedef float f32x4 __attribute__((ext_vector_type(4)));
typedef short s16x8 __attribute__((ext_vector_type(8)));

// static device scratch -- fully rewritten every call before use
__device__ float4 g_atoms[NNODE*5];
__device__ float4 g_ca[NNODE];
__device__ ushort g_wbf[NOUT*NFEAT];   // W_edge bf16, row-major [e][f]
__device__ ushort g_wpt[66*16];        // (W_pos.T + b_pos) bf16, [d][c]
__device__ int    g_nbr[NNODE*KNB];
__device__ float  g_dnb[NNODE*KNB];

__constant__ int cPA[24] = {0,2,3,4,1,1,1,1,0,0,0,4,4,3,0,2,3,4,2,3,4,2,3,2};
__constant__ int cPB[24] = {0,2,3,4,0,2,3,4,2,3,4,2,3,2,1,1,1,1,0,0,0,4,4,3};

__device__ __forceinline__ ushort f2bf(float x) {      // RNE (used for weights)
  unsigned u = __float_as_uint(x);
  u += 0x7fffu + ((u >> 16) & 1u);
  return (ushort)(u >> 16);
}

__device__ __forceinline__ unsigned long long shfl_xor_u64(unsigned long long x, int m) {
  unsigned hi = __shfl_xor((unsigned)(x >> 32), m, 64);
  unsigned lo = __shfl_xor((unsigned)(x & 0xffffffffu), m, 64);
  return ((unsigned long long)hi << 32) | lo;
}

// ---------------- kernel 0: prep (Cb/atoms) + W->bf16 + WposT table ----------------
__global__ void k_pre(const float* __restrict__ X, const float* __restrict__ W,
                      const float* __restrict__ Wpos, const float* __restrict__ bpos) {
  int blk = blockIdx.x, tid = threadIdx.x;
  if (blk < 16) {
    int t = blk*256 + tid;
    const float* p = X + (size_t)t*12;
    float nx=p[0],ny=p[1],nz=p[2];
    float cax=p[3],cay=p[4],caz=p[5];
    float cx=p[6],cy=p[7],cz=p[8];
    float ox=p[9],oy=p[10],oz=p[11];
    float bx=cax-nx, by=cay-ny, bz=caz-nz;
    float ex=cx-cax, ey=cy-cay, ez=cz-caz;
    float ax2 = by*ez - bz*ey;
    float ay2 = bz*ex - bx*ez;
    float az2 = bx*ey - by*ex;
    float cbx = -0.58273431f*ax2 + 0.56802827f*bx - 0.54067466f*ex + cax;
    float cby = -0.58273431f*ay2 + 0.56802827f*by - 0.54067466f*ey + cay;
    float cbz = -0.58273431f*az2 + 0.56802827f*bz - 0.54067466f*ez + caz;
    g_atoms[t*5+0] = make_float4(nx,ny,nz,0.f);
    g_atoms[t*5+1] = make_float4(cax,cay,caz,0.f);
    g_atoms[t*5+2] = make_float4(cx,cy,cz,0.f);
    g_atoms[t*5+3] = make_float4(ox,oy,oz,0.f);
    g_atoms[t*5+4] = make_float4(cbx,cby,cbz,0.f);
    g_ca[t] = make_float4(cax,cay,caz,0.f);
  } else if (blk < 224) {
    int t = (blk-16)*256 + tid;       // exactly 208*256 = 128*416
    g_wbf[t] = f2bf(W[t]);
  } else {
    int t = (blk-224)*256 + tid;
    if (t < 66*16) {
      int d = t >> 4, c = t & 15;
      g_wpt[t] = f2bf(Wpos[c*66 + d] + bpos[c]);
    }
  }
}

// ---------------- kernel 1: exact top-K (bit-exact keys, sorted-queue extraction) ----------------
__global__ __launch_bounds__(256) void k_topk(const float* __restrict__ mask,
                                              float* __restrict__ outIdx) {
  __shared__ float4 sca[LSEQ];             // xyz + mask in .w (16 KB)
  __shared__ unsigned qhi[4][64][17];      // 17 KB (odd-dword pitch: 2-way max)
  __shared__ unsigned qlo[4][64][17];      // 17 KB
  int b = blockIdx.y;
  for (int t = threadIdx.x; t < LSEQ; t += 256) {
    float4 c = g_ca[b*LSEQ + t];
    c.w = mask[b*LSEQ + t];
    sca[t] = c;
  }
  __syncthreads();
  int wv = threadIdx.x >> 6, lane = threadIdx.x & 63;
  int i = blockIdx.x*4 + wv;
  float4 ci = sca[i];
  float  mi = ci.w;

  float Dv[16]; float dmax = 0.f;
  #pragma unroll
  for (int q = 0; q < 16; ++q) {
    int j = lane + (q << 6);
    float4 cj = sca[j];
    // bit-exact vs XLA: separate mul/add (no FMA), correctly-rounded sqrt
    float dx = __fsub_rn(cj.x, ci.x);
    float dy = __fsub_rn(cj.y, ci.y);
    float dz = __fsub_rn(cj.z, ci.z);
    float s  = __fadd_rn(__fadd_rn(__fmul_rn(dx,dx), __fmul_rn(dy,dy)), __fmul_rn(dz,dz));
    float sq = __fsqrt_rn(__fadd_rn(s, 1e-6f));
    float d  = __fmul_rn(__fmul_rn(mi, cj.w), sq);
    Dv[q] = d;
    dmax = fmaxf(dmax, d);
  }
  #pragma unroll
  for (int o = 32; o; o >>= 1) dmax = fmaxf(dmax, __shfl_xor(dmax, o, 64));

  unsigned long long key[16];
  #pragma unroll
  for (int q = 0; q < 16; ++q) {
    int j = lane + (q << 6);
    float m2   = __fmul_rn(mi, sca[j].w);
    float dadj = __fadd_rn(Dv[q], __fmul_rn(__fsub_rn(1.0f, m2), dmax));
    key[q] = ((unsigned long long)__float_as_uint(dadj) << 32) | (unsigned)j;
  }

  // Batcher odd-even mergesort of the 16 per-lane keys (ascending), fully unrolled
  #pragma unroll
  for (int p = 1; p < 16; p <<= 1)
    #pragma unroll
    for (int k = p; k >= 1; k >>= 1)
      #pragma unroll
      for (int j = k & (p - 1); j + k < 16; j += 2*k)
        #pragma unroll
        for (int u = 0; u < k; ++u)
          if (u + j + k < 16 && ((u + j) / (2*p) == (u + j + k) / (2*p))) {
            unsigned long long a = key[u+j], c2 = key[u+j+k];
            if (a > c2) { key[u+j] = c2; key[u+j+k] = a; }
          }

  #pragma unroll
  for (int q = 0; q < 16; ++q) {
    qhi[wv][lane][q] = (unsigned)(key[q] >> 32);
    qlo[wv][lane][q] = (unsigned)key[q];
  }
  // no barrier: each lane re-reads only its own queue

  unsigned long long head = key[0];
  int pos = 0;
  size_t row = (size_t)(b*LSEQ + i);
  for (int k = 0; k < KNB; ++k) {
    unsigned long long m = head;
    #pragma unroll
    for (int o = 1; o < 64; o <<= 1) {
      unsigned long long other = shfl_xor_u64(m, o);
      m = (other < m) ? other : m;
    }
    if (lane == 0) {
      unsigned j = (unsigned)m;
      g_nbr[row*KNB + k] = (int)j;
      g_dnb[row*KNB + k] = __uint_as_float((unsigned)(m >> 32));
      outIdx[row*KNB + k] = (float)(int)j;
    }
    if (head == m) {                     // unique owner (keys globally distinct)
      ++pos;
      head = (pos < 16)
           ? (((unsigned long long)qhi[wv][lane][pos] << 32) | qlo[wv][lane][pos])
           : ~0ull;
    }
  }
}

// ---------------- kernel 2: features (bf16, swizzled LDS) + split-K MFMA + fused LN ----------------
__global__ __launch_bounds__(256, 4) void k_edge(
    const int* __restrict__ ridx, const int* __restrict__ chain,
    const float* __restrict__ lng, const float* __restrict__ lnb,
    float* __restrict__ out)
{
  __shared__ __align__(16) ushort featb[KNB*256];   // 24,576 B; 32B-slot XOR swizzle
  __shared__ float4 atN[KNB*5];
  __shared__ float4 atI[5];
  __shared__ int    snbr[KNB];
  __shared__ float  sdn[KNB];
  __shared__ int    sdd[KNB];
  __shared__ float2 sstat[KNB][4];
  __shared__ float2 rstat[KNB];

  int node = blockIdx.x;               // b*LSEQ + i
  int b = node >> 10;
  size_t ebase = (size_t)node * KNB;
  int t = threadIdx.x;

  if (t < KNB) { snbr[t] = g_nbr[ebase + t]; sdn[t] = g_dnb[ebase + t]; }
  if (t >= 64 && t < 69) atI[t-64] = g_atoms[node*5 + (t-64)];
  __syncthreads();

  if (t < KNB) {
    int j = snbr[t];
    int off = ridx[node] - ridx[b*LSEQ + j];
    bool same = (chain[node] == chain[b*LSEQ + j]);
    int dcl = min(max(off + 32, 0), 64);
    sdd[t] = same ? dcl : 65;
  }
  for (int u = t; u < KNB*5; u += 256) {
    int k = u / 5, a = u % 5;
    atN[u] = g_atoms[(b*LSEQ + snbr[k])*5 + a];
  }
  __syncthreads();

  // RBF writer: features for pair-index p land in 32B slot `slot`, XOR-swizzled by row
  auto rbf_store = [&](int k, int slot, float d) {
    float z0 = __fmaf_rn(d, 0.8f, -1.6f);      // z_m = 0.8*d - 1.6 - m
    union { s16x8 v; ushort us[8]; } a0, a1;
    #pragma unroll
    for (int m = 0; m < 8; ++m) {
      float za = z0 - (float)m;
      float zb = z0 - (float)(m + 8);
      a0.us[m] = (ushort)(__float_as_uint(__expf(-(za*za))) >> 16);  // trunc-to-bf16
      a1.us[m] = (ushort)(__float_as_uint(__expf(-(zb*zb))) >> 16);
    }
    ushort* fp = &featb[k*256 + ((slot ^ (k & 7)) << 4)];
    *(s16x8*)fp       = a0.v;
    *(s16x8*)(fp + 8) = a1.v;
  };

  // ---- pass 0 features: E_pos (slot 0) + RBF p=0..12 (slots 1..13)
  if (t < 96) {
    int k = t >> 1, h = t & 1;
    *(s16x8*)&featb[k*256 + ((0 ^ (k & 7)) << 4) + h*8] =
        *(const s16x8*)&g_wpt[sdd[k]*16 + h*8];
  }
  for (int u = t; u < KNB*13; u += 256) {
    int k = u / 13, p = u % 13;
    float d;
    if (p == 0) d = sdn[k];
    else {
      float4 A = atI[cPA[p-1]];
      float4 Bv = atN[k*5 + cPB[p-1]];
      float dx = A.x-Bv.x, dy = A.y-Bv.y, dz = A.z-Bv.z;
      d = sqrtf(dx*dx + dy*dy + dz*dz + 1e-6f);
    }
    rbf_store(k, p + 1, d);
  }
  __syncthreads();

  int ln = t & 63, wv = t >> 6;
  int fr = ln & 15, fq = ln >> 4;
  int n0 = wv * 32;
  f32x4 acc[3][2];
  #pragma unroll
  for (int mt = 0; mt < 3; ++mt) { acc[mt][0] = (f32x4)0.f; acc[mt][1] = (f32x4)0.f; }
  const ushort* w0 = &g_wbf[(n0 + fr)*NFEAT];
  const ushort* w1 = &g_wbf[(n0 + 16 + fr)*NFEAT];

  // ---- GEMM pass 0: features [0,224), 7 K-steps
  #pragma unroll
  for (int k0 = 0; k0 < 224; k0 += 32) {
    int kk = k0 + fq*8;
    s16x8 b0 = *(const s16x8*)&w0[kk];
    s16x8 b1 = *(const s16x8*)&w1[kk];
    #pragma unroll
    for (int mt = 0; mt < 3; ++mt) {
      int row = mt*16 + fr;
      s16x8 af = *(const s16x8*)&featb[row*256 + (((kk >> 4) ^ (fr & 7)) << 4) + (kk & 8)];
      acc[mt][0] = __builtin_amdgcn_mfma_f32_16x16x32_bf16(af, b0, acc[mt][0], 0, 0, 0);
      acc[mt][1] = __builtin_amdgcn_mfma_f32_16x16x32_bf16(af, b1, acc[mt][1], 0, 0, 0);
    }
  }
  __syncthreads();   // pass-0 reads done before overwrite

  // ---- pass 1 features: RBF p=13..24 (slots 0..11)
  for (int u = t; u < KNB*12; u += 256) {
    int k = u / 12, p = 13 + u % 12;
    float4 A = atI[cPA[p-1]];
    float4 Bv = atN[k*5 + cPB[p-1]];
    float dx = A.x-Bv.x, dy = A.y-Bv.y, dz = A.z-Bv.z;
    rbf_store(k, p - 13, sqrtf(dx*dx + dy*dy + dz*dz + 1e-6f));
  }
  __syncthreads();

  // ---- GEMM pass 1: features [224,416), 6 K-steps
  #pragma unroll
  for (int k0 = 0; k0 < 192; k0 += 32) {
    int kk = k0 + fq*8;
    s16x8 b0 = *(const s16x8*)&w0[224 + kk];
    s16x8 b1 = *(const s16x8*)&w1[224 + kk];
    #pragma unroll
    for (int mt = 0; mt < 3; ++mt) {
      int row = mt*16 + fr;
      s16x8 af = *(const s16x8*)&featb[row*256 + (((kk >> 4) ^ (fr & 7)) << 4) + (kk & 8)];
      acc[mt][0] = __builtin_amdgcn_mfma_f32_16x16x32_bf16(af, b0, acc[mt][0], 0, 0, 0);
      acc[mt][1] = __builtin_amdgcn_mfma_f32_16x16x32_bf16(af, b1, acc[mt][1], 0, 0, 0);
    }
  }

  // ---- fused LayerNorm epilogue (C/D layout: row = fq*4+i within tile, col = fr)
  #pragma unroll
  for (int mt = 0; mt < 3; ++mt)
    #pragma unroll
    for (int i2 = 0; i2 < 4; ++i2) {
      float v0 = acc[mt][0][i2], v1 = acc[mt][1][i2];
      float s = v0 + v1, sq = v0*v0 + v1*v1;
      #pragma unroll
      for (int o = 8; o; o >>= 1) { s += __shfl_xor(s, o, 64); sq += __shfl_xor(sq, o, 64); }
      if (fr == 0) sstat[mt*16 + fq*4 + i2][wv] = make_float2(s, sq);
    }
  __syncthreads();
  if (t < KNB) {
    float s = 0.f, sq = 0.f;
    #pragma unroll
    for (int w = 0; w < 4; ++w) { float2 pp = sstat[t][w]; s += pp.x; sq += pp.y; }
    float mu  = s * (1.0f/128.0f);
    float var = sq * (1.0f/128.0f) - mu*mu;
    rstat[t] = make_float2(mu, rsqrtf(var + 1e-5f));
  }
  __syncthreads();
  float gn0 = lng[n0+fr], gn1 = lng[n0+16+fr];
  float bn0 = lnb[n0+fr], bn1 = lnb[n0+16+fr];
  #pragma unroll
  for (int mt = 0; mt < 3; ++mt)
    #pragma unroll
    for (int i2 = 0; i2 < 4; ++i2) {
      int row = mt*16 + fq*4 + i2;
      float2 mr = rstat[row];
      size_t ob = (ebase + row) * NOUT;
      out[ob + n0 + fr]      = (acc[mt][0][i2] - mr.x) * mr.y * gn0 + bn0;
      out[ob + n0 + 16 + fr] = (acc[mt][1][i2] - mr.x) * mr.y * gn1 + bn1;
    }
}

extern "C" void kernel_launch(void* const* d_in, const int* in_sizes, int n_in,
                              void* d_out, int out_size, void* d_ws, size_t ws_size,
                              hipStream_t stream) {
  const float* X     = (const float*)d_in[0];
  const float* mask  = (const float*)d_in[1];
  const int*   ridx  = (const int*)d_in[2];
  const int*   chain = (const int*)d_in[3];
  const float* Wpos  = (const float*)d_in[4];
  const float* bpos  = (const float*)d_in[5];
  const float* Wedge = (const float*)d_in[6];
  const float* lng   = (const float*)d_in[7];
  const float* lnb   = (const float*)d_in[8];
  float* out = (float*)d_out;
  float* outIdx = out + (size_t)NNODE*KNB*NOUT;

  k_pre<<<dim3(229), dim3(256), 0, stream>>>(X, Wedge, Wpos, bpos);
  k_topk<<<dim3(LSEQ/4, NB), dim3(256), 0, stream>>>(mask, outIdx);
  k_edge<<<dim3(NNODE), dim3(256), 0, stream>>>(ridx, chain, lng, lnb, out);
}

// Round 5
// 82.969 us; speedup vs baseline: 9.4321x; 1.3350x over previous
//
#include <hip/hip_runtime.h>
#include <stdint.h>

#define LSEQ 1024
#define NB 4
#define KNB 48
#define NFEAT 416   // 16 + 25*16
#define NOUT 128
#define NNODE (NB*LSEQ)

typedef float f32x4 __attribute__((ext_vector_type(4)));
typedef short s16x8 __attribute__((ext_vector_type(8)));

// static device scratch -- fully rewritten every call before use
__device__ float4 g_atoms[NNODE*5];
__device__ ushort g_wbf[NOUT*NFEAT];   // W_edge bf16, row-major [e][f]
__device__ ushort g_wpt[66*16];        // (W_pos.T + b_pos) bf16, [d][c]
__device__ int    g_nbr[NNODE*KNB];
__device__ float  g_dnb[NNODE*KNB];

__constant__ int cPA[24] = {0,2,3,4,1,1,1,1,0,0,0,4,4,3,0,2,3,4,2,3,4,2,3,2};
__constant__ int cPB[24] = {0,2,3,4,0,2,3,4,2,3,4,2,3,2,1,1,1,1,0,0,0,4,4,3};
// c_m = m * (16/15) * sqrt(log2(e))  -- u_m = 0.96089793*d - 1.92179585 - c_m ; rbf = exp2(-u^2)
__constant__ float cC[16] = {
  0.0f, 1.28119724f, 2.56239447f, 3.84359171f,
  5.12478894f, 6.40598618f, 7.68718342f, 8.96838065f,
  10.24957789f, 11.53077512f, 12.81197236f, 14.09316960f,
  15.37436683f, 16.65556407f, 17.93676131f, 19.21795854f};

__device__ __forceinline__ ushort f2bf(float x) {      // RNE (weights)
  unsigned u = __float_as_uint(x);
  u += 0x7fffu + ((u >> 16) & 1u);
  return (ushort)(u >> 16);
}
// pack trunc-bf16(lo), trunc-bf16(hi) into one dword via byte-perm
__device__ __forceinline__ unsigned pack2bf(float lo, float hi) {
  return __builtin_amdgcn_perm(__float_as_uint(hi), __float_as_uint(lo), 0x07060302u);
}

#define DPP_ADD_F(x, CTRL) { int _y = __builtin_amdgcn_mov_dpp(__float_as_int(x), CTRL, 0xF, 0xF, true); x += __int_as_float(_y); }
#define DPP_MIN_U(x, CTRL) { unsigned _y = (unsigned)__builtin_amdgcn_mov_dpp((int)(x), CTRL, 0xF, 0xF, true); x = min(x, _y); }

__device__ __forceinline__ unsigned wave_umin(unsigned x) {
  DPP_MIN_U(x, 0x128) DPP_MIN_U(x, 0x124) DPP_MIN_U(x, 0x122) DPP_MIN_U(x, 0x121)
  x = min(x, (unsigned)__shfl_xor((int)x, 16, 64));
  x = min(x, (unsigned)__shfl_xor((int)x, 32, 64));
  return x;
}

// ---------------- kernel 1: prep blocks + exact top-K blocks, one dispatch ----------------
__global__ __launch_bounds__(256) void k_front(
    const float* __restrict__ X, const float* __restrict__ mask,
    const float* __restrict__ W, const float* __restrict__ Wpos,
    const float* __restrict__ bpos, float* __restrict__ outIdx)
{
  __shared__ float4 sca[LSEQ];             // xyz + mask in .w (16 KB)
  __shared__ unsigned qhi[4][64][17];
  __shared__ unsigned qlo[4][64][17];
  int blk = blockIdx.x, tid = threadIdx.x;

  if (blk >= 1024) {                       // ---- prep blocks
    int pb = blk - 1024;
    if (pb < 16) {                         // atoms + Cb
      int t = pb*256 + tid;
      const float* p = X + (size_t)t*12;
      float nx=p[0],ny=p[1],nz=p[2];
      float cax=p[3],cay=p[4],caz=p[5];
      float cx=p[6],cy=p[7],cz=p[8];
      float ox=p[9],oy=p[10],oz=p[11];
      float bx=cax-nx, by=cay-ny, bz=caz-nz;
      float ex=cx-cax, ey=cy-cay, ez=cz-caz;
      float ax2 = by*ez - bz*ey;
      float ay2 = bz*ex - bx*ez;
      float az2 = bx*ey - by*ex;
      float cbx = -0.58273431f*ax2 + 0.56802827f*bx - 0.54067466f*ex + cax;
      float cby = -0.58273431f*ay2 + 0.56802827f*by - 0.54067466f*ey + cay;
      float cbz = -0.58273431f*az2 + 0.56802827f*bz - 0.54067466f*ez + caz;
      g_atoms[t*5+0] = make_float4(nx,ny,nz,0.f);
      g_atoms[t*5+1] = make_float4(cax,cay,caz,0.f);
      g_atoms[t*5+2] = make_float4(cx,cy,cz,0.f);
      g_atoms[t*5+3] = make_float4(ox,oy,oz,0.f);
      g_atoms[t*5+4] = make_float4(cbx,cby,cbz,0.f);
    } else if (pb < 32) {                  // W_edge -> bf16 (16 blocks x 13 iters)
      int base = (pb-16)*3328 + tid;
      #pragma unroll
      for (int q = 0; q < 13; ++q) g_wbf[base + q*256] = f2bf(W[base + q*256]);
    } else {                               // WposT table
      for (int t = tid; t < 66*16; t += 256) {
        int d = t >> 4, c = t & 15;
        g_wpt[t] = f2bf(Wpos[c*66 + d] + bpos[c]);
      }
    }
    return;
  }

  // ---- top-K block
  int b = blk >> 8, chunk = blk & 255;
  for (int t = tid; t < LSEQ; t += 256) {
    const float* p = X + (size_t)(b*LSEQ + t)*12 + 3;   // Ca
    sca[t] = make_float4(p[0], p[1], p[2], mask[b*LSEQ + t]);
  }
  __syncthreads();
  int wv = tid >> 6, lane = tid & 63;
  int i = chunk*4 + wv;
  float4 ci = sca[i];
  float  mi = ci.w;

  float Dv[16]; float dmax = 0.f;
  #pragma unroll
  for (int q = 0; q < 16; ++q) {
    int j = lane + (q << 6);
    float4 cj = sca[j];
    // bit-exact vs XLA: separate mul/add (no FMA), correctly-rounded sqrt
    float dx = __fsub_rn(cj.x, ci.x);
    float dy = __fsub_rn(cj.y, ci.y);
    float dz = __fsub_rn(cj.z, ci.z);
    float s  = __fadd_rn(__fadd_rn(__fmul_rn(dx,dx), __fmul_rn(dy,dy)), __fmul_rn(dz,dz));
    float sq = __fsqrt_rn(__fadd_rn(s, 1e-6f));
    float d  = __fmul_rn(__fmul_rn(mi, cj.w), sq);
    Dv[q] = d;
    dmax = fmaxf(dmax, d);
  }
  #pragma unroll
  for (int o = 32; o; o >>= 1) dmax = fmaxf(dmax, __shfl_xor(dmax, o, 64));

  unsigned long long key[16];
  #pragma unroll
  for (int q = 0; q < 16; ++q) {
    int j = lane + (q << 6);
    float m2   = __fmul_rn(mi, sca[j].w);
    float dadj = __fadd_rn(Dv[q], __fmul_rn(__fsub_rn(1.0f, m2), dmax));
    key[q] = ((unsigned long long)__float_as_uint(dadj) << 32) | (unsigned)j;
  }

  // Batcher odd-even mergesort of the 16 per-lane keys (ascending)
  #pragma unroll
  for (int p = 1; p < 16; p <<= 1)
    #pragma unroll
    for (int k = p; k >= 1; k >>= 1)
      #pragma unroll
      for (int j = k & (p - 1); j + k < 16; j += 2*k)
        #pragma unroll
        for (int u = 0; u < k; ++u)
          if (u + j + k < 16 && ((u + j) / (2*p) == (u + j + k) / (2*p))) {
            unsigned long long a = key[u+j], c2 = key[u+j+k];
            if (a > c2) { key[u+j] = c2; key[u+j+k] = a; }
          }

  #pragma unroll
  for (int q = 0; q < 16; ++q) {
    qhi[wv][lane][q] = (unsigned)(key[q] >> 32);
    qlo[wv][lane][q] = (unsigned)key[q];
  }
  // no barrier: each lane re-reads only its own queue

  unsigned hhi = (unsigned)(key[0] >> 32), hlo = (unsigned)key[0];
  int pos = 0;
  size_t row = (size_t)(b*LSEQ + i);
  for (int k = 0; k < KNB; ++k) {
    unsigned mh = wave_umin(hhi);
    unsigned long long bmask = __ballot(hhi == mh);
    bool own;
    if (__popcll(bmask) == 1) {
      own = (hhi == mh);
    } else {                              // hi tie: min index wins
      unsigned jv = (hhi == mh) ? hlo : 0xFFFFFFFFu;
      unsigned mj = wave_umin(jv);
      own = (hhi == mh) && (hlo == mj);
    }
    if (own) {
      g_nbr[row*KNB + k] = (int)hlo;
      g_dnb[row*KNB + k] = __uint_as_float(mh);
      outIdx[row*KNB + k] = (float)(int)hlo;
      ++pos;
      if (pos < 16) { hhi = qhi[wv][lane][pos]; hlo = qlo[wv][lane][pos]; }
      else          { hhi = 0xFFFFFFFFu; hlo = 0xFFFFFFFFu; }
    }
  }
}

// ---------------- kernel 2: features (bf16, swizzled LDS) + pipelined MFMA + fused LN ----------------
__global__ __launch_bounds__(256, 4) void k_edge(
    const int* __restrict__ ridx, const int* __restrict__ chain,
    const float* __restrict__ lng, const float* __restrict__ lnb,
    float* __restrict__ out)
{
  __shared__ __align__(16) ushort featb[KNB*256];   // 24,576 B; 32B-slot XOR swizzle
  __shared__ float4 atN[KNB*5];
  __shared__ float4 atI[5];
  __shared__ float  sdn[KNB];
  __shared__ int    sdd[KNB];
  __shared__ float2 sstat[KNB][4];
  __shared__ float2 rstat[KNB];

  int node = blockIdx.x;               // b*LSEQ + i
  int b = node >> 10;
  size_t ebase = (size_t)node * KNB;
  int t = threadIdx.x;

  // ---- phase A: scalars + atom gather (single barrier)
  if (t < KNB) {
    int j = g_nbr[ebase + t];
    sdn[t] = g_dnb[ebase + t];
    int off = ridx[node] - ridx[b*LSEQ + j];
    bool same = (chain[node] == chain[b*LSEQ + j]);
    int dcl = min(max(off + 32, 0), 64);
    sdd[t] = same ? dcl : 65;
  }
  if (t >= 64 && t < 69) atI[t-64] = g_atoms[node*5 + (t-64)];
  for (int u = t; u < KNB*5; u += 256) {
    int k = u / 5, a = u % 5;
    atN[u] = g_atoms[(b*LSEQ + g_nbr[ebase + k])*5 + a];
  }
  __syncthreads();

  // RBF writer: 16 feats of pair p -> 32B slot, XOR-swizzled by row
  auto rbf_store = [&](int k, int slot, float d) {
    float u0 = __fmaf_rn(d, 0.96089793f, -1.92179585f);
    float e[16];
    #pragma unroll
    for (int m = 0; m < 16; ++m) {
      float u = u0 - cC[m];
      e[m] = __builtin_amdgcn_exp2f(-(u*u));
    }
    union { s16x8 v; unsigned w[4]; } a0, a1;
    #pragma unroll
    for (int q = 0; q < 4; ++q) {
      a0.w[q] = pack2bf(e[2*q],   e[2*q+1]);
      a1.w[q] = pack2bf(e[8+2*q], e[8+2*q+1]);
    }
    ushort* fp = &featb[k*256 + ((slot ^ (k & 7)) << 4)];
    *(s16x8*)fp       = a0.v;
    *(s16x8*)(fp + 8) = a1.v;
  };

  // ---- pass 0 features: E_pos (slot 0) + RBF p=0..12 (slots 1..13)
  if (t < 96) {
    int k = t >> 1, h = t & 1;
    *(s16x8*)&featb[k*256 + ((0 ^ (k & 7)) << 4) + h*8] =
        *(const s16x8*)&g_wpt[sdd[k]*16 + h*8];
  }
  for (int u = t; u < KNB*13; u += 256) {
    int k = u / 13, p = u % 13;
    float d;
    if (p == 0) d = sdn[k];
    else {
      float4 A = atI[cPA[p-1]];
      float4 Bv = atN[k*5 + cPB[p-1]];
      float dx = A.x-Bv.x, dy = A.y-Bv.y, dz = A.z-Bv.z;
      d = sqrtf(dx*dx + dy*dy + dz*dz + 1e-6f);
    }
    rbf_store(k, p + 1, d);
  }
  __syncthreads();

  int ln = t & 63, wv = t >> 6;
  int fr = ln & 15, fq = ln >> 4;
  int n0 = wv * 32;
  f32x4 acc[3][2];
  #pragma unroll
  for (int mt = 0; mt < 3; ++mt) { acc[mt][0] = (f32x4)0.f; acc[mt][1] = (f32x4)0.f; }
  const ushort* w0 = &g_wbf[(n0 + fr)*NFEAT];
  const ushort* w1 = &g_wbf[(n0 + 16 + fr)*NFEAT];

  // 2-stage-pipelined GEMM pass: featb local k from 0, W offset WOFF
#define GEMM_PASS(WOFF, NSTEPS)                                                     \
  {                                                                                 \
    s16x8 cw0 = *(const s16x8*)&w0[(WOFF) + fq*8];                                  \
    s16x8 cw1 = *(const s16x8*)&w1[(WOFF) + fq*8];                                  \
    _Pragma("unroll")                                                               \
    for (int s = 0; s < (NSTEPS); ++s) {                                            \
      int kk = s*32 + fq*8;                                                         \
      s16x8 nw0, nw1;                                                               \
      if (s + 1 < (NSTEPS)) {                                                       \
        nw0 = *(const s16x8*)&w0[(WOFF) + kk + 32];                                 \
        nw1 = *(const s16x8*)&w1[(WOFF) + kk + 32];                                 \
      }                                                                             \
      _Pragma("unroll")                                                             \
      for (int mt = 0; mt < 3; ++mt) {                                              \
        int row = mt*16 + fr;                                                       \
        s16x8 af = *(const s16x8*)&featb[row*256 + (((kk >> 4) ^ (fr & 7)) << 4) + (kk & 8)]; \
        acc[mt][0] = __builtin_amdgcn_mfma_f32_16x16x32_bf16(af, cw0, acc[mt][0], 0, 0, 0);   \
        acc[mt][1] = __builtin_amdgcn_mfma_f32_16x16x32_bf16(af, cw1, acc[mt][1], 0, 0, 0);   \
      }                                                                             \
      if (s + 1 < (NSTEPS)) { cw0 = nw0; cw1 = nw1; }                               \
    }                                                                               \
  }

  // ---- GEMM pass 0: features [0,224), 7 K-steps
  GEMM_PASS(0, 7)
  __syncthreads();   // pass-0 reads done before overwrite

  // ---- pass 1 features: RBF p=13..24 (slots 0..11)
  for (int u = t; u < KNB*12; u += 256) {
    int k = u / 12, p = 13 + u % 12;
    float4 A = atI[cPA[p-1]];
    float4 Bv = atN[k*5 + cPB[p-1]];
    float dx = A.x-Bv.x, dy = A.y-Bv.y, dz = A.z-Bv.z;
    rbf_store(k, p - 13, sqrtf(dx*dx + dy*dy + dz*dz + 1e-6f));
  }
  __syncthreads();

  // ---- GEMM pass 1: features [224,416), 6 K-steps
  GEMM_PASS(224, 6)

  // ---- fused LayerNorm epilogue; row sums via DPP row_ror (VALU-only)
  #pragma unroll
  for (int mt = 0; mt < 3; ++mt)
    #pragma unroll
    for (int i2 = 0; i2 < 4; ++i2) {
      float v0 = acc[mt][0][i2], v1 = acc[mt][1][i2];
      float s = v0 + v1, sq = v0*v0 + v1*v1;
      DPP_ADD_F(s, 0x128) DPP_ADD_F(s, 0x124) DPP_ADD_F(s, 0x122) DPP_ADD_F(s, 0x121)
      DPP_ADD_F(sq, 0x128) DPP_ADD_F(sq, 0x124) DPP_ADD_F(sq, 0x122) DPP_ADD_F(sq, 0x121)
      if (fr == 0) sstat[mt*16 + fq*4 + i2][wv] = make_float2(s, sq);
    }
  __syncthreads();
  if (t < KNB) {
    float s = 0.f, sq = 0.f;
    #pragma unroll
    for (int w = 0; w < 4; ++w) { float2 pp = sstat[t][w]; s += pp.x; sq += pp.y; }
    float mu  = s * (1.0f/128.0f);
    float var = sq * (1.0f/128.0f) - mu*mu;
    rstat[t] = make_float2(mu, rsqrtf(var + 1e-5f));
  }
  __syncthreads();
  float gn0 = lng[n0+fr], gn1 = lng[n0+16+fr];
  float bn0 = lnb[n0+fr], bn1 = lnb[n0+16+fr];
  #pragma unroll
  for (int mt = 0; mt < 3; ++mt)
    #pragma unroll
    for (int i2 = 0; i2 < 4; ++i2) {
      int row = mt*16 + fq*4 + i2;
      float2 mr = rstat[row];
      size_t ob = (ebase + row) * NOUT;
      out[ob + n0 + fr]      = (acc[mt][0][i2] - mr.x) * mr.y * gn0 + bn0;
      out[ob + n0 + 16 + fr] = (acc[mt][1][i2] - mr.x) * mr.y * gn1 + bn1;
    }
}

extern "C" void kernel_launch(void* const* d_in, const int* in_sizes, int n_in,
                              void* d_out, int out_size, void* d_ws, size_t ws_size,
                              hipStream_t stream) {
  const float* X     = (const float*)d_in[0];
  const float* mask  = (const float*)d_in[1];
  const int*   ridx  = (const int*)d_in[2];
  const int*   chain = (const int*)d_in[3];
  const float* Wpos  = (const float*)d_in[4];
  const float* bpos  = (const float*)d_in[5];
  const float* Wedge = (const float*)d_in[6];
  const float* lng   = (const float*)d_in[7];
  const float* lnb   = (const float*)d_in[8];
  float* out = (float*)d_out;
  float* outIdx = out + (size_t)NNODE*KNB*NOUT;

  k_front<<<dim3(1024 + 33), dim3(256), 0, stream>>>(X, mask, Wedge, Wpos, bpos, outIdx);
  k_edge<<<dim3(NNODE), dim3(256), 0, stream>>>(ridx, chain, lng, lnb, out);
}